// Round 1
// baseline (86.599 us; speedup 1.0000x reference)
//
#include <hip/hip_runtime.h>

#define NDESC 384
#define NTYPES 4
#define ATOMS_PER_CONF 64
#define BLOCK_ATOMS 256

typedef unsigned int uint32;
typedef unsigned long long u64;

// ---------------- Kernel 1: per-block type histogram ----------------
__global__ __launch_bounds__(BLOCK_ATOMS) void hist_kernel(
    const int* __restrict__ types, uint32* __restrict__ blockHist, int n) {
  __shared__ uint32 cnt[NTYPES];
  int tid = threadIdx.x;
  if (tid < NTYPES) cnt[tid] = 0;
  __syncthreads();
  int idx = blockIdx.x * BLOCK_ATOMS + tid;
  int ty = (idx < n) ? types[idx] : -1;
  int lane = tid & 63;
  for (int t = 0; t < NTYPES; ++t) {
    u64 m = __ballot(ty == t);
    if (lane == 0) atomicAdd(&cnt[t], (uint32)__popcll(m));
  }
  __syncthreads();
  if (tid < NTYPES) blockHist[blockIdx.x * NTYPES + tid] = cnt[tid];
}

// ---------------- Kernel 2: single-block scan over block histograms ----------
// blockDim = 256 (4 waves); wave w owns type w. Computes:
//   totals[t], base[t] (exclusive over types), blockOff[b][t] (stable offsets),
//   and writes at_type_count (as float) to outCounts.
__global__ __launch_bounds__(256) void scan_kernel(
    const uint32* __restrict__ blockHist, uint32* __restrict__ blockOff,
    float* __restrict__ outCounts, int nb) {
  __shared__ uint32 totals[NTYPES];
  int tid = threadIdx.x;
  int wave = tid >> 6;   // == type (4 waves)
  int lane = tid & 63;

  // per-type total
  uint32 sum = 0;
  for (int b = lane; b < nb; b += 64) sum += blockHist[b * NTYPES + wave];
  for (int off = 32; off > 0; off >>= 1) sum += __shfl_down(sum, off);
  if (lane == 0) totals[wave] = sum;
  __syncthreads();

  uint32 base = 0;
  for (int t = 0; t < wave; ++t) base += totals[t];

  // exclusive scan across blocks for this type, 64 blocks per chunk
  uint32 carry = 0;
  for (int c = 0; c * 64 < nb; ++c) {
    int b = c * 64 + lane;
    uint32 v = (b < nb) ? blockHist[b * NTYPES + wave] : 0;
    uint32 orig = v;
    for (int off = 1; off < 64; off <<= 1) {
      uint32 nv = __shfl_up(v, off);
      if (lane >= off) v += nv;
    }
    if (b < nb) blockOff[b * NTYPES + wave] = base + carry + (v - orig);
    carry += __shfl(v, 63);
  }
  if (tid < NTYPES) outCounts[tid] = (float)totals[tid];
}

// ---------------- Kernel 3: fused rank + descriptor + scatter ----------------
// blockDim = 384. Threads 0..255 compute stable ranks for the block's 256
// atoms; then all 384 threads write descriptor rows (lane d writes element d,
// 1536 B contiguous per row).
__global__ __launch_bounds__(384) void main_kernel(
    const float* __restrict__ coords, const int* __restrict__ types,
    const float* __restrict__ W, const uint32* __restrict__ blockOff,
    float* __restrict__ descOut, float* __restrict__ confOut, int n) {
  __shared__ float sW[3 * NDESC];
  __shared__ float sC[BLOCK_ATOMS][3];
  __shared__ uint32 sPos[BLOCK_ATOMS];
  __shared__ int sValid[BLOCK_ATOMS];
  __shared__ uint32 waveCnt[BLOCK_ATOMS / 64][NTYPES];

  int tid = threadIdx.x;
  int base = blockIdx.x * BLOCK_ATOMS;

  // stage W (3x384) and this block's coords (256x3)
  for (int i = tid; i < 3 * NDESC; i += 384) sW[i] = W[i];
  for (int i = tid; i < BLOCK_ATOMS * 3; i += 384) {
    int g = base * 3 + i;
    sC[i / 3][i % 3] = (g < n * 3) ? coords[g] : 0.0f;
  }

  // phase 1: stable rank within block via wave ballots
  int idx = base + tid;
  int ty = -1;
  if (tid < BLOCK_ATOMS && idx < n) ty = types[idx];
  int wave = tid >> 6, lane = tid & 63;
  int myrank = 0;
  if (tid < BLOCK_ATOMS) {
    for (int t = 0; t < NTYPES; ++t) {
      u64 m = __ballot(ty == t);
      if (lane == 0) waveCnt[wave][t] = (uint32)__popcll(m);
      if (t == ty) myrank = (int)__popcll(m & ((1ull << lane) - 1ull));
    }
  }
  __syncthreads();
  if (tid < BLOCK_ATOMS) {
    if (ty >= 0) {
      for (int w = 0; w < wave; ++w) myrank += (int)waveCnt[w][ty];
      uint32 pos = blockOff[blockIdx.x * NTYPES + ty] + (uint32)myrank;
      sPos[tid] = pos;
      sValid[tid] = 1;
      confOut[pos] = (float)(idx / ATOMS_PER_CONF);
    } else {
      sPos[tid] = 0;
      sValid[tid] = 0;
    }
  }
  __syncthreads();

  // phase 2: descriptor rows. d = tid (0..383), loop-invariant W in registers.
  float w0 = sW[tid];
  float w1 = sW[NDESC + tid];
  float w2 = sW[2 * NDESC + tid];
  for (int a = 0; a < BLOCK_ATOMS; ++a) {
    if (!sValid[a]) continue;
    float c0 = sC[a][0], c1 = sC[a][1], c2 = sC[a][2];
    float x = c0 * w0 + c1 * w1 + c2 * w2;
    float v = tanhf(x);
    descOut[(size_t)sPos[a] * NDESC + tid] = v;
  }
}

extern "C" void kernel_launch(void* const* d_in, const int* in_sizes, int n_in,
                              void* d_out, int out_size, void* d_ws, size_t ws_size,
                              hipStream_t stream) {
  const float* coords = (const float*)d_in[0];
  const int* types = (const int*)d_in[1];
  const float* W = (const float*)d_in[2];

  int n = in_sizes[1];                      // total atoms (= n_confs * 64)
  int nb = (n + BLOCK_ATOMS - 1) / BLOCK_ATOMS;

  uint32* blockHist = (uint32*)d_ws;        // nb * 4 uints
  uint32* blockOff = blockHist + (size_t)nb * NTYPES;  // nb * 4 uints

  float* descOut = (float*)d_out;
  float* confOut = descOut + (size_t)n * NDESC;
  float* countsOut = confOut + n;

  hipLaunchKernelGGL(hist_kernel, dim3(nb), dim3(BLOCK_ATOMS), 0, stream,
                     types, blockHist, n);
  hipLaunchKernelGGL(scan_kernel, dim3(1), dim3(256), 0, stream,
                     blockHist, blockOff, countsOut, nb);
  hipLaunchKernelGGL(main_kernel, dim3(nb), dim3(384), 0, stream,
                     coords, types, W, blockOff, descOut, confOut, n);
}

// Round 3
// 52.045 us; speedup vs baseline: 1.6639x; 1.6639x over previous
//
#include <hip/hip_runtime.h>

#define NDESC 384
#define NTYPES 4
#define ATOMS_PER_CONF 64
#define BLOCK_ATOMS 256

typedef unsigned int uint32;
typedef unsigned long long u64;

// tanh(x) = 1 - 2/(1+e^{2x}); native v_exp_f32 + v_rcp_f32. Saturates to
// +/-1 for large |x|, no NaN for finite x. Abs err ~1e-6.
__device__ __forceinline__ float fast_tanh(float x) {
  float e = __builtin_amdgcn_exp2f(x * 2.8853900817779268f);   // e^{2x}
  return 1.0f - 2.0f * __builtin_amdgcn_rcpf(1.0f + e);
}

// ---------------- Kernel 1: per-block type histogram ----------------
__global__ __launch_bounds__(BLOCK_ATOMS) void hist_kernel(
    const int* __restrict__ types, uint32* __restrict__ blockHist, int n) {
  __shared__ uint32 cnt[NTYPES];
  int tid = threadIdx.x;
  if (tid < NTYPES) cnt[tid] = 0;
  __syncthreads();
  int idx = blockIdx.x * BLOCK_ATOMS + tid;
  int ty = (idx < n) ? types[idx] : -1;
  int lane = tid & 63;
  for (int t = 0; t < NTYPES; ++t) {
    u64 m = __ballot(ty == t);
    if (lane == 0) atomicAdd(&cnt[t], (uint32)__popcll(m));
  }
  __syncthreads();
  if (tid < NTYPES) blockHist[blockIdx.x * NTYPES + tid] = cnt[tid];
}

// ---------------- Kernel 2: single-block scan over block histograms ----------
__global__ __launch_bounds__(256) void scan_kernel(
    const uint32* __restrict__ blockHist, uint32* __restrict__ blockOff,
    float* __restrict__ outCounts, int nb) {
  __shared__ uint32 totals[NTYPES];
  int tid = threadIdx.x;
  int wave = tid >> 6;   // == type (4 waves)
  int lane = tid & 63;

  uint32 sum = 0;
  for (int b = lane; b < nb; b += 64) sum += blockHist[b * NTYPES + wave];
  for (int off = 32; off > 0; off >>= 1) sum += __shfl_down(sum, off);
  if (lane == 0) totals[wave] = sum;
  __syncthreads();

  uint32 base = 0;
  for (int t = 0; t < wave; ++t) base += totals[t];

  uint32 carry = 0;
  for (int c = 0; c * 64 < nb; ++c) {
    int b = c * 64 + lane;
    uint32 v = (b < nb) ? blockHist[b * NTYPES + wave] : 0;
    uint32 orig = v;
    for (int off = 1; off < 64; off <<= 1) {
      uint32 nv = __shfl_up(v, off);
      if (lane >= off) v += nv;
    }
    if (b < nb) blockOff[b * NTYPES + wave] = base + carry + (v - orig);
    carry += __shfl(v, 63);
  }
  if (tid < NTYPES) outCounts[tid] = (float)totals[tid];
}

// ---------------- Kernel 3: fused rank + descriptor + scatter ----------------
// blockDim = 384. Phase 1: threads 0..255 compute stable ranks for the block's
// 256 atoms. Phase 2: 4 rows in flight, 96 threads per row, each thread
// computes 4 descriptor columns and stores one float4 (wave-contiguous).
__global__ __launch_bounds__(384) void main_kernel(
    const float* __restrict__ coords, const int* __restrict__ types,
    const float* __restrict__ W, const uint32* __restrict__ blockOff,
    float* __restrict__ descOut, float* __restrict__ confOut, int n) {
  __shared__ float sW[3 * NDESC];
  __shared__ float sC[BLOCK_ATOMS][3];
  __shared__ uint32 sPos[BLOCK_ATOMS];
  __shared__ int sValid[BLOCK_ATOMS];
  __shared__ uint32 waveCnt[BLOCK_ATOMS / 64][NTYPES];

  int tid = threadIdx.x;
  int base = blockIdx.x * BLOCK_ATOMS;

  // stage W (3x384) and this block's coords (256x3)
  for (int i = tid; i < 3 * NDESC; i += 384) sW[i] = W[i];
  for (int i = tid; i < BLOCK_ATOMS * 3; i += 384) {
    int g = base * 3 + i;
    sC[i / 3][i % 3] = (g < n * 3) ? coords[g] : 0.0f;
  }

  // phase 1: stable rank within block via wave ballots
  int idx = base + tid;
  int ty = -1;
  if (tid < BLOCK_ATOMS && idx < n) ty = types[idx];
  int wave = tid >> 6, lane = tid & 63;
  int myrank = 0;
  if (tid < BLOCK_ATOMS) {
    for (int t = 0; t < NTYPES; ++t) {
      u64 m = __ballot(ty == t);
      if (lane == 0) waveCnt[wave][t] = (uint32)__popcll(m);
      if (t == ty) myrank = (int)__popcll(m & ((1ull << lane) - 1ull));
    }
  }
  __syncthreads();
  if (tid < BLOCK_ATOMS) {
    if (ty >= 0) {
      for (int w = 0; w < wave; ++w) myrank += (int)waveCnt[w][ty];
      uint32 pos = blockOff[blockIdx.x * NTYPES + ty] + (uint32)myrank;
      sPos[tid] = pos;
      sValid[tid] = 1;
      confOut[pos] = (float)(idx >> 6);   // idx / ATOMS_PER_CONF
    } else {
      sPos[tid] = 0;
      sValid[tid] = 0;
    }
  }
  __syncthreads();

  // phase 2: 4 rows x 96 threads; thread handles cols [4c, 4c+4)
  int r = tid / 96;        // row slot 0..3
  int c = tid - r * 96;    // 0..95
  int d0 = 4 * c;
  float w00 = sW[d0], w01 = sW[d0 + 1], w02 = sW[d0 + 2], w03 = sW[d0 + 3];
  float w10 = sW[NDESC + d0], w11 = sW[NDESC + d0 + 1],
        w12 = sW[NDESC + d0 + 2], w13 = sW[NDESC + d0 + 3];
  float w20 = sW[2 * NDESC + d0], w21 = sW[2 * NDESC + d0 + 1],
        w22 = sW[2 * NDESC + d0 + 2], w23 = sW[2 * NDESC + d0 + 3];

  for (int a0 = 0; a0 < BLOCK_ATOMS; a0 += 4) {
    int a = a0 + r;
    float c0 = sC[a][0], c1 = sC[a][1], c2 = sC[a][2];
    float4 v;
    v.x = fast_tanh(c0 * w00 + c1 * w10 + c2 * w20);
    v.y = fast_tanh(c0 * w01 + c1 * w11 + c2 * w21);
    v.z = fast_tanh(c0 * w02 + c1 * w12 + c2 * w22);
    v.w = fast_tanh(c0 * w03 + c1 * w13 + c2 * w23);
    if (sValid[a]) {
      *reinterpret_cast<float4*>(descOut + (size_t)sPos[a] * NDESC + d0) = v;
    }
  }
}

extern "C" void kernel_launch(void* const* d_in, const int* in_sizes, int n_in,
                              void* d_out, int out_size, void* d_ws, size_t ws_size,
                              hipStream_t stream) {
  const float* coords = (const float*)d_in[0];
  const int* types = (const int*)d_in[1];
  const float* W = (const float*)d_in[2];

  int n = in_sizes[1];                      // total atoms (= n_confs * 64)
  int nb = (n + BLOCK_ATOMS - 1) / BLOCK_ATOMS;

  uint32* blockHist = (uint32*)d_ws;        // nb * 4 uints
  uint32* blockOff = blockHist + (size_t)nb * NTYPES;  // nb * 4 uints

  float* descOut = (float*)d_out;
  float* confOut = descOut + (size_t)n * NDESC;
  float* countsOut = confOut + n;

  hipLaunchKernelGGL(hist_kernel, dim3(nb), dim3(BLOCK_ATOMS), 0, stream,
                     types, blockHist, n);
  hipLaunchKernelGGL(scan_kernel, dim3(1), dim3(256), 0, stream,
                     blockHist, blockOff, countsOut, nb);
  hipLaunchKernelGGL(main_kernel, dim3(nb), dim3(384), 0, stream,
                     coords, types, W, blockOff, descOut, confOut, n);
}